// Round 3
// baseline (542.656 us; speedup 1.0000x reference)
//
#include <hip/hip_runtime.h>

// Round 3: gate-specialized waves + XOR bank swizzle.
// Pass 1: convert input/hidden/5 weights fp32->bf16 into ws (unchanged).
// Pass 2: block = 128 rows x 64 cols, 4 waves.
//   waves 0,1: input gates {r_i, z_i, n_i}, 128 rows x 32 cols each (Mw=128,Nw=32)
//   waves 2,3: hidden gates {r_h, n_h},     128 rows x 32 cols each
// FLOP/LDS-byte: 49.2 avg (vs 26.7 in round 2). Epilogue exchanges the two
// hidden-gate planes via LDS in two 64-row chunks.

typedef __attribute__((ext_vector_type(8))) short          bf16x8;
typedef __attribute__((ext_vector_type(8))) unsigned short u16x8;
typedef __attribute__((ext_vector_type(4))) float          f32x4;

__device__ __forceinline__ unsigned short f2bf(float f) {
    union { float f; unsigned u; } v; v.f = f;
    unsigned r = v.u + 0x7FFFu + ((v.u >> 16) & 1u);  // RNE
    return (unsigned short)(r >> 16);
}

// ---- Pass 1: fp32 -> bf16 into ws ----
// ws elements: [0) input 16777216 | [16777216) hidden | [33554432 + g*1048576) W_g
// gate order g: 0=r_i 1=r_h 2=z_i 3=n_i 4=n_h
__global__ __launch_bounds__(256) void convert_bf16(
    const float* __restrict__ in0, const float* __restrict__ in1,
    const float* __restrict__ w0, const float* __restrict__ w1,
    const float* __restrict__ w2, const float* __restrict__ w3,
    const float* __restrict__ w4, unsigned short* __restrict__ ws)
{
    const long long e = ((long long)blockIdx.x * 256 + threadIdx.x) * 8;
    const float* src;
    if (e < 16777216LL) {
        src = in0 + e;
    } else if (e < 33554432LL) {
        src = in1 + (e - 16777216LL);
    } else {
        const long long t = e - 33554432LL;
        const int g = (int)(t >> 20);
        const long long within = t & 1048575LL;
        const float* w = (g == 0) ? w0 : (g == 1) ? w1 : (g == 2) ? w2 : (g == 3) ? w3 : w4;
        src = w + within;
    }
    const float4 a = *reinterpret_cast<const float4*>(src);
    const float4 b = *reinterpret_cast<const float4*>(src + 4);
    u16x8 o;
    o[0] = f2bf(a.x); o[1] = f2bf(a.y); o[2] = f2bf(a.z); o[3] = f2bf(a.w);
    o[4] = f2bf(b.x); o[5] = f2bf(b.y); o[6] = f2bf(b.z); o[7] = f2bf(b.w);
    *reinterpret_cast<u16x8*>(ws + e) = o;
}

__device__ __forceinline__ void async16(const void* g, void* l) {
    __builtin_amdgcn_global_load_lds(
        (const __attribute__((address_space(1))) unsigned int*)g,
        (__attribute__((address_space(3))) unsigned int*)l, 16, 0, 0);
}

// LDS image (bf16): [0,8192) sIn[128][32] | [8192,16384) sHid[128][32] |
// [16384,36864) sW[5][64][32]. Rows are 64 B; within each row the four 16B
// k-chunks are XOR-swizzled by (row ^ row>>2) to spread frag reads over banks.
__global__ __launch_bounds__(256, 2) void gru_fused(
    const unsigned short* __restrict__ bf,
    const float* __restrict__ hidden,
    const float* __restrict__ b_ri, const float* __restrict__ b_rh,
    const float* __restrict__ b_zi, const float* __restrict__ b_ni,
    const float* __restrict__ b_nh,
    float* __restrict__ out)
{
    __shared__ __align__(16) unsigned char sBuf[36864];

    const int tid  = threadIdx.x;
    const int wave = tid >> 6;
    const int lane = tid & 63;
    const int quad = lane >> 4;
    const int l16  = lane & 15;

    const int row0 = blockIdx.y * 128;
    const int col0 = blockIdx.x * 64;

    // physical k-chunk for all fragment reads (mi/ni-invariant)
    const int kchunk = (quad ^ (l16 & 3) ^ ((l16 >> 2) & 3)) & 3;

    // DMA source offsets (elements into bf) for the 9 slots of this thread.
    int srcoff[9];
    #pragma unroll
    for (int j = 0; j < 9; ++j) {
        const int s = (j * 4 + wave) * 64 + lane;
        if (s < 512) {
            const int r = s >> 2, qh = s & 3;
            const int p = (qh ^ r ^ (r >> 2)) & 3;            // swizzled fetch
            srcoff[j] = (row0 + r) * 1024 + p * 8;
        } else if (s < 1024) {
            const int r = (s - 512) >> 2, qh = s & 3;
            const int p = (qh ^ r ^ (r >> 2)) & 3;
            srcoff[j] = 16777216 + (row0 + r) * 1024 + p * 8;
        } else {
            const int t = s - 1024;
            const int g = t >> 8, tt = t & 255;
            const int n = tt >> 2, qh = tt & 3;
            const int p = (qh ^ n ^ (n >> 2)) & 3;
            srcoff[j] = 33554432 + g * 1048576 + (col0 + n) * 1024 + p * 8;
        }
    }
    const int ldsbase = wave * 1024 + lane * 16;  // + j*4096 per slot

    const bool isInput = (wave < 2);
    const int  nbase   = (wave & 1) * 32;

    // fragment base addresses
    const int abase = (isInput ? 0 : 8192) + l16 * 64 + kchunk * 16;
    const int bb    = 16384 + nbase * 64 + l16 * 64 + kchunk * 16;
    const int bOff0 = bb + (isInput ? 0 : 1) * 4096;   // r_i | r_h
    const int bOff1 = bb + (isInput ? 2 : 4) * 4096;   // z_i | n_h
    const int bOff2 = bb + 3 * 4096;                   // n_i (input only)

    f32x4 acc[3][8][2];
    #pragma unroll
    for (int g = 0; g < 3; ++g)
        #pragma unroll
        for (int mi = 0; mi < 8; ++mi)
            #pragma unroll
            for (int ni = 0; ni < 2; ++ni)
                acc[g][mi][ni] = (f32x4){0.f, 0.f, 0.f, 0.f};

    for (int k0 = 0; k0 < 1024; k0 += 32) {
        __syncthreads();
        #pragma unroll
        for (int j = 0; j < 9; ++j)
            async16(bf + srcoff[j] + k0, sBuf + ldsbase + j * 4096);
        __syncthreads();

        if (isInput) {
            bf16x8 B[3][2];
            #pragma unroll
            for (int ni = 0; ni < 2; ++ni) {
                B[0][ni] = *reinterpret_cast<const bf16x8*>(&sBuf[bOff0 + ni * 1024]);
                B[1][ni] = *reinterpret_cast<const bf16x8*>(&sBuf[bOff1 + ni * 1024]);
                B[2][ni] = *reinterpret_cast<const bf16x8*>(&sBuf[bOff2 + ni * 1024]);
            }
            #pragma unroll
            for (int mi = 0; mi < 8; ++mi) {
                const bf16x8 A = *reinterpret_cast<const bf16x8*>(&sBuf[abase + mi * 1024]);
                #pragma unroll
                for (int g = 0; g < 3; ++g)
                    #pragma unroll
                    for (int ni = 0; ni < 2; ++ni)
                        acc[g][mi][ni] = __builtin_amdgcn_mfma_f32_16x16x32_bf16(A, B[g][ni], acc[g][mi][ni], 0, 0, 0);
            }
        } else {
            bf16x8 B[2][2];
            #pragma unroll
            for (int ni = 0; ni < 2; ++ni) {
                B[0][ni] = *reinterpret_cast<const bf16x8*>(&sBuf[bOff0 + ni * 1024]);
                B[1][ni] = *reinterpret_cast<const bf16x8*>(&sBuf[bOff1 + ni * 1024]);
            }
            #pragma unroll
            for (int mi = 0; mi < 8; ++mi) {
                const bf16x8 A = *reinterpret_cast<const bf16x8*>(&sBuf[abase + mi * 1024]);
                #pragma unroll
                for (int g = 0; g < 2; ++g)
                    #pragma unroll
                    for (int ni = 0; ni < 2; ++ni)
                        acc[g][mi][ni] = __builtin_amdgcn_mfma_f32_16x16x32_bf16(A, B[g][ni], acc[g][mi][ni], 0, 0, 0);
            }
        }
    }

    // ---- epilogue: exchange hidden-gate planes via LDS, 2 chunks of 64 rows ----
    // eBuf: 2 planes x 64 rows x 68 floats (pad 4) = 34816 B, overlaid on sBuf.
    float* eBuf = reinterpret_cast<float*>(sBuf);

    float bA[2], bB[2], bC[2];
    #pragma unroll
    for (int ni = 0; ni < 2; ++ni) {
        const int gcol = col0 + nbase + ni * 16 + l16;
        if (isInput) { bA[ni] = b_ri[gcol]; bB[ni] = b_zi[gcol]; bC[ni] = b_ni[gcol]; }
        else         { bA[ni] = b_rh[gcol]; bB[ni] = b_nh[gcol]; bC[ni] = 0.f; }
    }

    __syncthreads();  // all frag reads done before overwriting sBuf

    #pragma unroll
    for (int c = 0; c < 2; ++c) {
        if (!isInput) {
            #pragma unroll
            for (int mc = 0; mc < 4; ++mc) {
                const int mi = c * 4 + mc;
                #pragma unroll
                for (int ni = 0; ni < 2; ++ni) {
                    const int colB = nbase + ni * 16 + l16;
                    #pragma unroll
                    for (int r4 = 0; r4 < 4; ++r4) {
                        const int rowc = mc * 16 + quad * 4 + r4;
                        eBuf[rowc * 68 + colB]        = acc[0][mi][ni][r4] + bA[ni];  // r_h + b_rh
                        eBuf[4352 + rowc * 68 + colB] = acc[1][mi][ni][r4] + bB[ni];  // n_h + b_nh
                    }
                }
            }
        }
        __syncthreads();
        if (isInput) {
            #pragma unroll
            for (int mc = 0; mc < 4; ++mc) {
                const int mi = c * 4 + mc;
                #pragma unroll
                for (int ni = 0; ni < 2; ++ni) {
                    const int colB = nbase + ni * 16 + l16;
                    const int gcol = col0 + colB;
                    #pragma unroll
                    for (int r4 = 0; r4 < 4; ++r4) {
                        const int rowc = mc * 16 + quad * 4 + r4;
                        const int grow = row0 + mi * 16 + quad * 4 + r4;
                        const float rh = eBuf[rowc * 68 + colB];
                        const float nh = eBuf[4352 + rowc * 68 + colB];
                        const float rr = 1.f / (1.f + __expf(-(acc[0][mi][ni][r4] + bA[ni] + rh)));
                        const float zz = 1.f / (1.f + __expf(-(acc[1][mi][ni][r4] + bB[ni] + rh)));
                        const float nn = tanhf(acc[2][mi][ni][r4] + bC[ni] + rr * nh);
                        const float h  = hidden[grow * 1024 + gcol];
                        const float o  = (1.f - zz) * nn + zz * h;
                        out[grow * 1024 + gcol]            = o;
                        out[16777216 + grow * 1024 + gcol] = o;
                    }
                }
            }
        }
        __syncthreads();
    }
}

extern "C" void kernel_launch(void* const* d_in, const int* in_sizes, int n_in,
                              void* d_out, int out_size, void* d_ws, size_t ws_size,
                              hipStream_t stream) {
    const float* input  = (const float*)d_in[0];
    const float* hidden = (const float*)d_in[1];
    const float* W_ri = (const float*)d_in[2];
    const float* b_ri = (const float*)d_in[3];
    const float* W_rh = (const float*)d_in[4];
    const float* b_rh = (const float*)d_in[5];
    const float* W_zi = (const float*)d_in[6];
    const float* b_zi = (const float*)d_in[7];
    // d_in[8], d_in[9] = W_z_h, b_z_h: dead per the reference's bug (z uses r_h)
    const float* W_ni = (const float*)d_in[10];
    const float* b_ni = (const float*)d_in[11];
    const float* W_nh = (const float*)d_in[12];
    const float* b_nh = (const float*)d_in[13];
    float* out = (float*)d_out;
    unsigned short* ws = (unsigned short*)d_ws;

    convert_bf16<<<18944, 256, 0, stream>>>(input, hidden, W_ri, W_rh, W_zi, W_ni, W_nh, ws);

    dim3 grid(16, 128);
    gru_fused<<<grid, 256, 0, stream>>>(ws, hidden, b_ri, b_rh, b_zi, b_ni, b_nh, out);
}